// Round 6
// baseline (194.272 us; speedup 1.0000x reference)
//
#include <hip/hip_runtime.h>
#include <hip/hip_bf16.h>
#include <stdint.h>

typedef unsigned short u16;
typedef __attribute__((ext_vector_type(8))) __bf16 bvec8;
typedef __attribute__((ext_vector_type(4))) float f32x4;
typedef __attribute__((ext_vector_type(16))) float f32x16;

__device__ __forceinline__ u16 f32_to_bf16(float f) {
    uint32_t u = __float_as_uint(f);
    u += 0x7fffu + ((u >> 16) & 1u);   // RNE
    return (u16)(u >> 16);
}
__device__ __forceinline__ uint32_t pack_bf16x2(float lo, float hi) {
    union { __hip_bfloat162 h; uint32_t u; } c;
    c.h = __float22bfloat162_rn(make_float2(lo, hi));   // x -> low 16 bits
    return c.u;
}

// async global->LDS, 16B/lane; LDS dest = wave-uniform base + lane*16 (HW rule)
__device__ __forceinline__ void gl2lds16(const u16* g, u16* l) {
    void* gnc = const_cast<void*>((const void*)g);
    __builtin_amdgcn_global_load_lds(
        (__attribute__((address_space(1))) uint32_t*)gnc,
        (__attribute__((address_space(3))) uint32_t*)((void*)l),
        16, 0, 0);
}

// ---------------------------------------------------------------------------
// fp32 -> bf16 for all three inputs in one launch
// ---------------------------------------------------------------------------
__global__ __launch_bounds__(256) void cvt3(
    const float* __restrict__ a, int na4, const float* __restrict__ b, int nb4,
    const float* __restrict__ c, int nc4,
    u16* __restrict__ oa, u16* __restrict__ ob, u16* __restrict__ oc)
{
    int i = blockIdx.x * 256 + threadIdx.x;
    const float* src; u16* dst; int off;
    if (i < na4)             { src = a; dst = oa; off = i; }
    else if (i < na4 + nb4)  { src = b; dst = ob; off = i - na4; }
    else if (i < na4 + nb4 + nc4) { src = c; dst = oc; off = i - na4 - nb4; }
    else return;
    float4 v = ((const float4*)src)[off];
    ushort4 o;
    o.x = f32_to_bf16(v.x); o.y = f32_to_bf16(v.y);
    o.z = f32_to_bf16(v.z); o.w = f32_to_bf16(v.w);
    ((ushort4*)dst)[off] = o;
}

// ---------------------------------------------------------------------------
// GEMM (B^T): C[M][N] = A[M][K]*B[N][K]^T + bias[N]; bf16 in, fp32 acc.
// BM=128, BK=32, BNt template (128 or 64). 256 thr = 4 waves as 2x2.
// ---------------------------------------------------------------------------
template <int BNt, bool OUT_BF16>
__global__ __launch_bounds__(256) void gemm_bt_bias(
    const u16* __restrict__ A, const u16* __restrict__ B,
    const float* __restrict__ bias, void* __restrict__ Cv,
    int M, int N, int K)
{
    constexpr int NT = BNt / 32;
    __shared__ __attribute__((aligned(16))) u16 As[128 * 32];
    __shared__ __attribute__((aligned(16))) u16 Bs[BNt * 32];

    const int tid = threadIdx.x, wave = tid >> 6, lane = tid & 63;
    const int col = lane & 15, quad = lane >> 4;
    const int m0 = blockIdx.y * 128, n0 = blockIdx.x * BNt;
    const int wm = (wave >> 1) * 64, wn = (wave & 1) * (BNt / 2);
    const int srow = lane >> 2, schunk = lane & 3;
    const u16* Ag = A + (size_t)(m0 + wave * 32) * K;

    f32x4 acc[4][NT];
#pragma unroll
    for (int i = 0; i < 4; i++)
#pragma unroll
        for (int j = 0; j < NT; j++) acc[i][j] = f32x4{0.f, 0.f, 0.f, 0.f};

    for (int k0 = 0; k0 < K; k0 += 32) {
        __syncthreads();
        gl2lds16(Ag + (size_t)(srow)      * K + k0 + schunk * 8, &As[(wave * 2 + 0) * 512]);
        gl2lds16(Ag + (size_t)(16 + srow) * K + k0 + schunk * 8, &As[(wave * 2 + 1) * 512]);
        if constexpr (BNt == 128) {
            const u16* Bg = B + (size_t)(n0 + wave * 32) * K;
            gl2lds16(Bg + (size_t)(srow)      * K + k0 + schunk * 8, &Bs[(wave * 2 + 0) * 512]);
            gl2lds16(Bg + (size_t)(16 + srow) * K + k0 + schunk * 8, &Bs[(wave * 2 + 1) * 512]);
        } else {
            const u16* Bg = B + (size_t)(n0 + wave * 16) * K;
            gl2lds16(Bg + (size_t)(srow)      * K + k0 + schunk * 8, &Bs[wave * 512]);
        }
        __syncthreads();

        bvec8 af[4], bfv[NT];
#pragma unroll
        for (int mt = 0; mt < 4; mt++)  af[mt]  = *(const bvec8*)&As[(wm + mt * 16 + col) * 32 + quad * 8];
#pragma unroll
        for (int nt = 0; nt < NT; nt++) bfv[nt] = *(const bvec8*)&Bs[(wn + nt * 16 + col) * 32 + quad * 8];
#pragma unroll
        for (int mt = 0; mt < 4; mt++)
#pragma unroll
            for (int nt = 0; nt < NT; nt++)
                acc[mt][nt] = __builtin_amdgcn_mfma_f32_16x16x32_bf16(af[mt], bfv[nt], acc[mt][nt], 0, 0, 0);
    }

#pragma unroll
    for (int mt = 0; mt < 4; mt++) {
#pragma unroll
        for (int r = 0; r < 4; r++) {
            const int m = m0 + wm + mt * 16 + quad * 4 + r;
#pragma unroll
            for (int nt = 0; nt < NT; nt++) {
                const int n = n0 + wn + nt * 16 + col;
                float v = acc[mt][nt][r] + bias[n];
                if (OUT_BF16) ((u16*)Cv)[(size_t)m * N + n] = f32_to_bf16(v);
                else          ((float*)Cv)[(size_t)m * N + n] = v;
            }
        }
    }
}

// ---------------------------------------------------------------------------
// V transpose with sigma-interleave: vT[b][h][d][64*blk + p] = V[64*blk + s(p)][d]
// where s(p) = (p&32) | ((p&1)<<4) | ((p>>1)&15)  (pairs (s,s+16) adjacent)
// ---------------------------------------------------------------------------
__global__ __launch_bounds__(256) void transpose_v(const u16* __restrict__ qkv,
                                                   u16* __restrict__ vT)
{
    __shared__ u16 Ts[64 * 74];
    const int tid = threadIdx.x;
    const int t0 = blockIdx.x * 64, h = blockIdx.y, b = blockIdx.z;
    const u16* src = qkv + (size_t)b * 2048 * 3072 + 2048 + h * 64;
#pragma unroll
    for (int k2 = 0; k2 < 2; k2++) {
        int c = k2 * 256 + tid, tl = c >> 3, ch = c & 7;
        *(uint4*)&Ts[tl * 74 + ch * 8] = *(const uint4*)(src + (size_t)(t0 + tl) * 3072 + ch * 8);
    }
    __syncthreads();
    u16* dst = vT + (size_t)((b * 16 + h) * 64) * 2048;
#pragma unroll
    for (int k2 = 0; k2 < 2; k2++) {
        int c = k2 * 256 + tid, d = c >> 3, tch = c & 7;
        u16 tmp[8];
#pragma unroll
        for (int j2 = 0; j2 < 8; j2++) {
            int p  = tch * 8 + j2;
            int sl = (p & 32) | ((p & 1) << 4) | ((p >> 1) & 15);
            tmp[j2] = Ts[sl * 74 + d];
        }
        *(uint4*)&dst[(size_t)d * 2048 + t0 + tch * 8] = *(const uint4*)tmp;
    }
}

// ---------------------------------------------------------------------------
// Flash attention, 32x32x16 MFMA, S^T orientation, zero-LDS P transpose.
// Block = complementary qt-pair (s_idx, 31-s_idx), 64 q-rows; 4 waves as
// (q-half wq) x (s-half ws). Grid (32 bh, 16 pairs) -> same-head blocks on
// one XCD. K/V double-buffered gl2lds, s_waitcnt vmcnt(4) prefetch.
// ---------------------------------------------------------------------------
__global__ __launch_bounds__(256) void attn_kernel(const u16* __restrict__ qkv,
                                                   const u16* __restrict__ vT,
                                                   u16* __restrict__ Y)
{
    __shared__ __attribute__((aligned(16))) u16 Qs[64 * 64];
    __shared__ __attribute__((aligned(16))) u16 Ks[2][64 * 64];
    __shared__ __attribute__((aligned(16))) u16 Vs[2][64 * 64];
    __shared__ __attribute__((aligned(16))) float Obuf[2][64][36];  // [wq][d][q-padded]
    __shared__ __attribute__((aligned(16))) float Lbuf[2][2][32];   // [ws][wq][q]

    const int tid = threadIdx.x, wave = tid >> 6, lane = tid & 63;
    const int l31 = lane & 31, hi = lane >> 5;
    const int wq = wave >> 1, ws = wave & 1;

    const int g = blockIdx.x;                // b*16 + h
    const int b = g >> 4, h = g & 15;
    const int s_idx = blockIdx.y;

    const u16* qb = qkv + (size_t)b * 2048 * 3072;
    const u16* vb = vT + (size_t)g * 64 * 2048;

    // staging source params (16B units, XOR chunk swizzle)
    const int c0 = wave * 64 + lane, c1 = 256 + c0;
    const int r0 = c0 >> 3, p0c = c0 & 7, r1 = c1 >> 3, p1c = c1 & 7;
    const int sw0 = (p0c ^ (r0 & 7)) * 8, sw1 = (p1c ^ (r1 & 7)) * 8;

    const int q_lane = wq * 32 + l31;        // local q-row owned by this lane
    const int s_lane = ws * 32 + l31;        // local s-row (K) read by this lane

#pragma unroll
    for (int phase = 0; phase < 2; ++phase) {
        const int qt = phase ? (31 - s_idx) : s_idx;
        const int q0 = qt * 64;

        __syncthreads();   // previous phase fully done (incl. combine reads)
        // stage Q, then prologue K/V tile 0 (prefetch)
        gl2lds16(qb + (size_t)(q0 + r0) * 3072 + h * 64 + sw0, &Qs[wave * 512]);
        gl2lds16(qb + (size_t)(q0 + r1) * 3072 + h * 64 + sw1, &Qs[2048 + wave * 512]);
        gl2lds16(qb + (size_t)(r0) * 3072 + 1024 + h * 64 + sw0, &Ks[0][wave * 512]);
        gl2lds16(qb + (size_t)(r1) * 3072 + 1024 + h * 64 + sw1, &Ks[0][2048 + wave * 512]);
        gl2lds16(vb + (size_t)r0 * 2048 + sw0, &Vs[0][wave * 512]);
        gl2lds16(vb + (size_t)r1 * 2048 + sw1, &Vs[0][2048 + wave * 512]);
        asm volatile("s_waitcnt vmcnt(4)" ::: "memory");   // Q landed; K/V0 in flight
        asm volatile("s_barrier" ::: "memory");

        // Q B-fragments (n=q, k=d), persistent for the phase
        bvec8 qf[4];
#pragma unroll
        for (int c = 0; c < 4; c++)
            qf[c] = *(const bvec8*)&Qs[q_lane * 64 + (((c * 2 + hi) ^ (q_lane & 7)) * 8)];

        float l_acc = 0.f;
        f32x16 o0, o1;
#pragma unroll
        for (int i = 0; i < 16; i++) { o0[i] = 0.f; o1[i] = 0.f; }

        for (int kt = 0; kt <= qt; ++kt) {
            const int cur = kt & 1;
            if (kt < qt) {
                const int s0n = (kt + 1) * 64, nb2 = cur ^ 1;
                gl2lds16(qb + (size_t)(s0n + r0) * 3072 + 1024 + h * 64 + sw0, &Ks[nb2][wave * 512]);
                gl2lds16(qb + (size_t)(s0n + r1) * 3072 + 1024 + h * 64 + sw1, &Ks[nb2][2048 + wave * 512]);
                gl2lds16(vb + (size_t)r0 * 2048 + s0n + sw0, &Vs[nb2][wave * 512]);
                gl2lds16(vb + (size_t)r1 * 2048 + s0n + sw1, &Vs[nb2][2048 + wave * 512]);
                asm volatile("s_waitcnt vmcnt(4)" ::: "memory");
            } else {
                asm volatile("s_waitcnt vmcnt(0)" ::: "memory");
            }
            asm volatile("s_barrier" ::: "memory");

            const bool diag = (kt == qt);
            if (!(diag && wq == 0 && ws == 1)) {   // that wave is fully masked on diag
                // S^T = K * Q^T : D[m=s][n=q], one 32x32 tile per wave
                f32x16 sv;
#pragma unroll
                for (int i = 0; i < 16; i++) sv[i] = 0.f;
#pragma unroll
                for (int c = 0; c < 4; c++) {
                    bvec8 kf = *(const bvec8*)&Ks[cur][s_lane * 64 + (((c * 2 + hi) ^ (s_lane & 7)) * 8)];
                    sv = __builtin_amdgcn_mfma_f32_32x32x16_bf16(kf, qf[c], sv, 0, 0, 0);
                }

                // p = exp(S/8) via exp2; causal mask on diag tile
                float pv[16];
                if (diag) {
                    const int s_base = kt * 64 + ws * 32 + 4 * hi;
                    const int q_act  = q0 + wq * 32 + l31;
#pragma unroll
                    for (int i = 0; i < 16; i++) {
                        float p = exp2f(sv[i] * 0.1803368801f);
                        int s_act = s_base + (i & 3) + 8 * (i >> 2);
                        if (s_act > q_act) p = 0.f;
                        pv[i] = p;
                    }
                } else {
#pragma unroll
                    for (int i = 0; i < 16; i++)
                        pv[i] = exp2f(sv[i] * 0.1803368801f);
                }
                // l accumulate (tree)
                {
                    float t0a = (pv[0] + pv[1]) + (pv[2] + pv[3]);
                    float t1a = (pv[4] + pv[5]) + (pv[6] + pv[7]);
                    float t2a = (pv[8] + pv[9]) + (pv[10] + pv[11]);
                    float t3a = (pv[12] + pv[13]) + (pv[14] + pv[15]);
                    l_acc += (t0a + t1a) + (t2a + t3a);
                }

                // sigma-pack pairs (s, s+16) -> PV A-fragments, entirely in-register
                uint32_t w[8];
#pragma unroll
                for (int i = 0; i < 8; i++) w[i] = pack_bf16x2(pv[i], pv[i + 8]);
                union { uint32_t u[4]; bvec8 v; } pf0, pf1;
                pf0.u[0] = w[0]; pf0.u[1] = w[1]; pf0.u[2] = w[2]; pf0.u[3] = w[3];
                pf1.u[0] = w[4]; pf1.u[1] = w[5]; pf1.u[2] = w[6]; pf1.u[3] = w[7];

                // O += P * V^T : D[m=q][n=d]; V^T staged in sigma order
#pragma unroll
                for (int ch = 0; ch < 2; ch++) {
                    bvec8 pf = ch ? pf1.v : pf0.v;
                    const int lc = ws * 4 + ch * 2 + hi;          // logical 16B chunk
                    const int d0r = l31;
                    bvec8 vf0 = *(const bvec8*)&Vs[cur][d0r * 64 + ((lc ^ (d0r & 7)) * 8)];
                    o0 = __builtin_amdgcn_mfma_f32_32x32x16_bf16(pf, vf0, o0, 0, 0, 0);
                    const int d1r = 32 + l31;
                    bvec8 vf1 = *(const bvec8*)&Vs[cur][d1r * 64 + ((lc ^ (d1r & 7)) * 8)];
                    o1 = __builtin_amdgcn_mfma_f32_32x32x16_bf16(pf, vf1, o1, 0, 0, 0);
                }
            }
            asm volatile("s_barrier" ::: "memory");   // readers done before buf reuse
        }

        // ---- phase epilogue: combine s-halves, normalize, store ----
        l_acc += __shfl_xor(l_acc, 32);               // sum the two hi-halves (same q)
        __syncthreads();
        if (lane < 32) Lbuf[ws][wq][lane] = l_acc;
        if (ws == 0) {
#pragma unroll
            for (int nt = 0; nt < 2; nt++) {
                const int d = nt * 32 + l31;
#pragma unroll
                for (int g4 = 0; g4 < 4; g4++) {
                    f32x4 v;
#pragma unroll
                    for (int j = 0; j < 4; j++) v[j] = nt ? o1[g4 * 4 + j] : o0[g4 * 4 + j];
                    *(f32x4*)&Obuf[wq][d][8 * g4 + 4 * hi] = v;
                }
            }
        }
        __syncthreads();
        if (ws == 1) {
            float inv[16];
#pragma unroll
            for (int g4 = 0; g4 < 4; g4++) {
                f32x4 la = *(const f32x4*)&Lbuf[0][wq][8 * g4 + 4 * hi];
                f32x4 lb = *(const f32x4*)&Lbuf[1][wq][8 * g4 + 4 * hi];
#pragma unroll
                for (int j = 0; j < 4; j++) inv[g4 * 4 + j] = 1.0f / (la[j] + lb[j]);
            }
#pragma unroll
            for (int nt = 0; nt < 2; nt++) {
                const int d = nt * 32 + l31;
#pragma unroll
                for (int g4 = 0; g4 < 4; g4++) {
                    f32x4 po = *(const f32x4*)&Obuf[wq][d][8 * g4 + 4 * hi];
#pragma unroll
                    for (int j = 0; j < 4; j++) {
                        const int i = g4 * 4 + j;
                        float val = ((nt ? o1[i] : o0[i]) + po[j]) * inv[i];
                        const int t = q0 + wq * 32 + 8 * g4 + 4 * hi + j;
                        Y[(size_t)(b * 2048 + t) * 1024 + h * 64 + d] = f32_to_bf16(val);
                    }
                }
            }
        }
    }
}

// ---------------------------------------------------------------------------
extern "C" void kernel_launch(void* const* d_in, const int* in_sizes, int n_in,
                              void* d_out, int out_size, void* d_ws, size_t ws_size,
                              hipStream_t stream) {
    const float* x      = (const float*)d_in[0];
    const float* w_attn = (const float*)d_in[1];
    const float* b_attn = (const float*)d_in[2];
    const float* w_proj = (const float*)d_in[3];
    const float* b_proj = (const float*)d_in[4];
    float* out = (float*)d_out;

    u16* xb  = (u16*)d_ws;
    u16* wab = xb  + (size_t)4096 * 1024;
    u16* wpb = wab + (size_t)3072 * 1024;
    u16* qkv = wpb + (size_t)1024 * 1024;
    u16* y   = qkv + (size_t)4096 * 3072;
    u16* vT  = xb;                               // reuse: dead after GEMM1

    const int na4 = 4096 * 1024 / 4, nb4 = 3072 * 1024 / 4, nc4 = 1024 * 1024 / 4;
    cvt3<<<(na4 + nb4 + nc4 + 255) / 256, 256, 0, stream>>>(
        x, na4, w_attn, nb4, w_proj, nc4, xb, wab, wpb);

    dim3 g1(3072 / 128, 4096 / 128);
    gemm_bt_bias<128, true><<<g1, 256, 0, stream>>>(xb, wab, b_attn, qkv, 4096, 3072, 1024);

    dim3 gt(32, 16, 2);
    transpose_v<<<gt, 256, 0, stream>>>(qkv, vT);

    dim3 g2(32, 16, 1);   // x = b*16+h (XCD-local K/V), y = pair index
    attn_kernel<<<g2, 256, 0, stream>>>(qkv, vT, y);

    dim3 g3(1024 / 64, 4096 / 128);
    gemm_bt_bias<64, false><<<g3, 256, 0, stream>>>(y, wpb, b_proj, out, 4096, 1024, 1024);
}